// Round 3
// baseline (1118.852 us; speedup 1.0000x reference)
//
#include <hip/hip_runtime.h>
#include <hip/hip_bf16.h>
#include <stdint.h>

// Problem constants
#define B_  2
#define S_  2048
#define H_  4096
#define NQ_ 32
#define NKV_ 8
#define D_  128
#define NQKV_ 6144   // (NQ+2*NKV)*D

typedef __bf16 bf16_t;
typedef __bf16 bf16x8 __attribute__((ext_vector_type(8)));
typedef float  floatx4 __attribute__((ext_vector_type(4)));

#define GLOBAL_AS __attribute__((address_space(1)))
#define LDS_AS    __attribute__((address_space(3)))

// ---------------------------------------------------------------------------
// f32 -> bf16 elementwise convert (vectorized: 4 elems/thread)
// ---------------------------------------------------------------------------
__global__ __launch_bounds__(256) void convert_f32_bf16(
    const float* __restrict__ src, bf16_t* __restrict__ dst, int n4) {
  int i = blockIdx.x * 256 + threadIdx.x;
  if (i < n4) {
    float4 v = ((const float4*)src)[i];
    bf16_t o[4] = {(bf16_t)v.x, (bf16_t)v.y, (bf16_t)v.z, (bf16_t)v.w};
    ((uint64_t*)dst)[i] = *(const uint64_t*)o;
  }
}

// ---------------------------------------------------------------------------
// Transpose + convert: src f32 [R][C] -> dst bf16 [C][R], 64x64 LDS tiles
// ---------------------------------------------------------------------------
__global__ __launch_bounds__(256) void transpose_f32_bf16(
    const float* __restrict__ src, bf16_t* __restrict__ dst, int R, int C) {
  __shared__ bf16_t tile[64][65];
  const int ct = blockIdx.x * 64, rt = blockIdx.y * 64;
  const int t = threadIdx.x;
  const int cl = t & 63;
  for (int i = 0; i < 16; ++i) {
    int rl = i * 4 + (t >> 6);
    tile[rl][cl] = (bf16_t)src[(size_t)(rt + rl) * C + ct + cl];
  }
  __syncthreads();
  const int rl2 = t & 63;
  for (int i = 0; i < 16; ++i) {
    int cl2 = i * 4 + (t >> 6);
    dst[(size_t)(ct + cl2) * R + rt + rl2] = tile[rl2][cl2];
  }
}

// ---------------------------------------------------------------------------
// GEMM: C[M,N] = A[M,K] * Bt[N,K]^T   (bf16 in, OutT out, fp32 accum)
// m97 structure: 128x128 tile, BK=32, 4 waves each 64x64 (4x4 of 16x16),
// global_load_lds width 16 staging.
// ---------------------------------------------------------------------------
template <typename OutT>
__global__ __launch_bounds__(256) void gemm_abt(
    const bf16_t* __restrict__ A, const bf16_t* __restrict__ Bt,
    OutT* __restrict__ C, int M, int N, int K) {
  __shared__ __align__(16) bf16_t lA[128 * 32];
  __shared__ __align__(16) bf16_t lB[128 * 32];
  const int tid = threadIdx.x;
  const int wave = tid >> 6, lane = tid & 63;
  const int lrow = lane & 15, quad = lane >> 4;
  const int row0 = blockIdx.y * 128, col0 = blockIdx.x * 128;
  const int wm = (wave >> 1) * 64, wn = (wave & 1) * 64;
  const int rA = lane >> 2;        // row-in-chunk = lane/4
  const int kA = (lane & 3) * 8;   // k offset = (lane%4)*8

  floatx4 acc[4][4] = {};

  for (int kt = 0; kt < K; kt += 32) {
    __syncthreads();
    for (int j = 0; j < 2; ++j) {
      const int c = wave * 2 + j;  // chunk 0..7, wave-uniform
      const bf16_t* ga = A  + (size_t)(row0 + c * 16 + rA) * K + kt + kA;
      const bf16_t* gb = Bt + (size_t)(col0 + c * 16 + rA) * K + kt + kA;
      __builtin_amdgcn_global_load_lds((GLOBAL_AS void*)ga,
                                       (LDS_AS void*)(lA + c * 512), 16, 0, 0);
      __builtin_amdgcn_global_load_lds((GLOBAL_AS void*)gb,
                                       (LDS_AS void*)(lB + c * 512), 16, 0, 0);
    }
    __syncthreads();
    bf16x8 af[4], bfr[4];
    for (int i = 0; i < 4; ++i)
      af[i] = *(const bf16x8*)(lA + (wm + i * 16 + lrow) * 32 + quad * 8);
    for (int j = 0; j < 4; ++j)
      bfr[j] = *(const bf16x8*)(lB + (wn + j * 16 + lrow) * 32 + quad * 8);
    for (int i = 0; i < 4; ++i)
      for (int j = 0; j < 4; ++j)
        acc[i][j] = __builtin_amdgcn_mfma_f32_16x16x32_bf16(af[i], bfr[j],
                                                            acc[i][j], 0, 0, 0);
  }

  // epilogue: C/D layout col=lane&15, row=quad*4+reg
  for (int i = 0; i < 4; ++i)
    for (int j = 0; j < 4; ++j)
      for (int r = 0; r < 4; ++r) {
        int row = row0 + wm + i * 16 + quad * 4 + r;
        int col = col0 + wn + j * 16 + lrow;
        C[(size_t)row * N + col] = (OutT)acc[i][j][r];
      }
}

// ---------------------------------------------------------------------------
// RoPE (GPT-J interleaved) on q,k + layout transform
// qkv[B*S][6144] -> Q[B][NQ][S][D], K[B][NKV][S][D]
// ---------------------------------------------------------------------------
__global__ __launch_bounds__(256) void rope_qk(
    const bf16_t* __restrict__ qkv, const int* __restrict__ positions,
    bf16_t* __restrict__ Q, bf16_t* __restrict__ K) {
  const int row = blockIdx.x;                 // b*S + s
  const int b = row >> 11, s = row & (S_ - 1);
  const float pos = (float)positions[row];
  const bf16_t* src = qkv + (size_t)row * NQKV_;
  for (int p = threadIdx.x; p < (NQ_ + NKV_) * 64; p += 256) {
    const int head = p >> 6, i = p & 63;
    const float inv = __powf(10000.0f, -(float)i * (1.0f / 64.0f));
    const float f = pos * inv;
    const float cs = __cosf(f), sn = __sinf(f);
    // q heads 0..31 at col head*128; k heads 32..39 at col 4096+(head-32)*128
    // == head*128 in both cases.
    const float x1 = (float)src[head * 128 + 2 * i];
    const float x2 = (float)src[head * 128 + 2 * i + 1];
    const float o1 = x1 * cs - x2 * sn;
    const float o2 = x2 * cs + x1 * sn;
    bf16_t* dst;
    if (head < NQ_)
      dst = Q + ((size_t)(b * NQ_ + head) * S_ + s) * D_ + 2 * i;
    else
      dst = K + ((size_t)(b * NKV_ + (head - NQ_)) * S_ + s) * D_ + 2 * i;
    dst[0] = (bf16_t)o1;
    dst[1] = (bf16_t)o2;
  }
}

// ---------------------------------------------------------------------------
// Extract V from qkv and transpose: qkv cols [5120,6144) -> Vt[B][NKV][D][S]
// ---------------------------------------------------------------------------
__global__ __launch_bounds__(256) void v_transpose(
    const bf16_t* __restrict__ qkv, bf16_t* __restrict__ Vt) {
  __shared__ bf16_t tile[64][65];
  const int b = blockIdx.z;
  const int kh = blockIdx.y >> 1;
  const int dt = (blockIdx.y & 1) * 64;
  const int st = blockIdx.x * 64;
  const int t = threadIdx.x;
  const int colbase = (NQ_ + NKV_) * D_ + kh * D_ + dt;  // 5120 + ...
  for (int i = 0; i < 16; ++i) {
    int sl = i * 4 + (t >> 6);
    int dl = t & 63;
    tile[sl][dl] = qkv[(size_t)(b * S_ + st + sl) * NQKV_ + colbase + dl];
  }
  __syncthreads();
  for (int i = 0; i < 16; ++i) {
    int dl = i * 4 + (t >> 6);
    int sl = t & 63;
    Vt[((size_t)(b * NKV_ + kh) * D_ + dt + dl) * S_ + st + sl] = tile[sl][dl];
  }
}

// ---------------------------------------------------------------------------
// Flash attention: causal, GQA (kh = h/4), online softmax.
// Q[B][NQ][S][D], K[B][NKV][S][D], Vt[B][NKV][D][S] -> O[B][S][NQ*D]
// Block = 256 thr (4 waves); BLOCK_M=64 (16 rows/wave), BLOCK_N=64.
// ---------------------------------------------------------------------------
__global__ __launch_bounds__(256) void flash_attn(
    const bf16_t* __restrict__ Q, const bf16_t* __restrict__ K,
    const bf16_t* __restrict__ Vt, bf16_t* __restrict__ O) {
  const int qt = blockIdx.x;   // q tile 0..31
  const int h  = blockIdx.y;   // 0..31
  const int b  = blockIdx.z;   // 0..1
  const int kh = h >> 2;
  const int tid = threadIdx.x, wave = tid >> 6, lane = tid & 63;
  const int lrow = lane & 15, quad = lane >> 4;
  const int q0 = qt * 64;

  __shared__ __align__(16) bf16_t lK[64][136];   // [s][d] padded (+8)
  __shared__ __align__(16) bf16_t lV[128][72];   // [d][s] padded (+8)
  __shared__ __align__(16) bf16_t lP[64][72];    // [m][s] padded (+8)

  const bf16_t* Qbase = Q  + ((size_t)(b * NQ_ + h) * S_) * D_;
  const bf16_t* Kbase = K  + ((size_t)(b * NKV_ + kh) * S_) * D_;
  const bf16_t* Vbase = Vt + ((size_t)(b * NKV_ + kh) * D_) * S_;

  // Q fragments (A-operand): row = q0 + wave*16 + lrow, k = ks*32 + quad*8
  bf16x8 qf[4];
  {
    const bf16_t* qp = Qbase + (size_t)(q0 + wave * 16 + lrow) * D_ + quad * 8;
    for (int ks = 0; ks < 4; ++ks) qf[ks] = *(const bf16x8*)(qp + ks * 32);
  }

  floatx4 acc[8] = {};
  float mrun[4], lrun[4];
  for (int r = 0; r < 4; ++r) { mrun[r] = -3.0e38f; lrun[r] = 0.0f; }
  const float scale = 0.08838834764831845f;  // 1/sqrt(128)

  const int nkt = qt + 1;
  for (int kt = 0; kt < nkt; ++kt) {
    const int k0 = kt * 64;
    __syncthreads();
    // stage K tile 64x128
    for (int it = 0; it < 4; ++it) {
      int idx = tid + it * 256;          // 0..1023
      int r = idx >> 4;                  // 0..63
      int d = (idx & 15) * 8;
      *(bf16x8*)&lK[r][d] = *(const bf16x8*)(Kbase + (size_t)(k0 + r) * D_ + d);
    }
    // stage V^T tile 128x64
    for (int it = 0; it < 4; ++it) {
      int idx = tid + it * 256;          // 0..1023
      int d = idx >> 3;                  // 0..127
      int s = (idx & 7) * 8;
      *(bf16x8*)&lV[d][s] = *(const bf16x8*)(Vbase + (size_t)d * S_ + k0 + s);
    }
    __syncthreads();

    // S = Q K^T : wave rows wave*16..+15 vs 64 cols (4 j-tiles)
    floatx4 sacc[4];
    for (int j = 0; j < 4; ++j) {
      floatx4 a = {0.f, 0.f, 0.f, 0.f};
      for (int ks = 0; ks < 4; ++ks) {
        bf16x8 kf = *(const bf16x8*)&lK[j * 16 + lrow][ks * 32 + quad * 8];
        a = __builtin_amdgcn_mfma_f32_16x16x32_bf16(qf[ks], kf, a, 0, 0, 0);
      }
      sacc[j] = a;
    }

    // online softmax per row (rows r: global qi = q0 + wave*16 + quad*4 + r)
    for (int r = 0; r < 4; ++r) {
      const int qi = q0 + wave * 16 + quad * 4 + r;
      float sv[4];
      float mx = -3.0e38f;
      for (int j = 0; j < 4; ++j) {
        float v = sacc[j][r] * scale;
        int kj = k0 + j * 16 + lrow;
        if (kj > qi) v = -1.0e30f;       // causal mask
        sv[j] = v;
        mx = fmaxf(mx, v);
      }
      for (int m = 1; m < 16; m <<= 1) mx = fmaxf(mx, __shfl_xor(mx, m));
      const float mnew = fmaxf(mrun[r], mx);
      const float alpha = __expf(mrun[r] - mnew);
      float rs = 0.0f;
      for (int j = 0; j < 4; ++j) {
        float p = __expf(sv[j] - mnew);
        rs += p;
        lP[wave * 16 + quad * 4 + r][j * 16 + lrow] = (bf16_t)p;
      }
      for (int m = 1; m < 16; m <<= 1) rs += __shfl_xor(rs, m);
      lrun[r] = lrun[r] * alpha + rs;
      mrun[r] = mnew;
      for (int dj = 0; dj < 8; ++dj) acc[dj][r] *= alpha;
    }
    // no barrier needed: each wave reads only its own lP rows (wave-synchronous)

    // O += P(16x64) V(64x128)
    bf16x8 pf[2];
    for (int ks = 0; ks < 2; ++ks)
      pf[ks] = *(const bf16x8*)&lP[wave * 16 + lrow][ks * 32 + quad * 8];
    for (int dj = 0; dj < 8; ++dj) {
      floatx4 a = acc[dj];
      for (int ks = 0; ks < 2; ++ks) {
        bf16x8 vf = *(const bf16x8*)&lV[dj * 16 + lrow][ks * 32 + quad * 8];
        a = __builtin_amdgcn_mfma_f32_16x16x32_bf16(pf[ks], vf, a, 0, 0, 0);
      }
      acc[dj] = a;
    }
  }

  // epilogue: normalize and write O[b][s][h*128+d]
  for (int dj = 0; dj < 8; ++dj) {
    for (int r = 0; r < 4; ++r) {
      const int m = wave * 16 + quad * 4 + r;
      const int d = dj * 16 + lrow;
      const float v = acc[dj][r] / lrun[r];
      O[((size_t)(b * S_) + q0 + m) * (NQ_ * D_) + h * D_ + d] = (bf16_t)v;
    }
  }
}

// ---------------------------------------------------------------------------
// Launch
// ---------------------------------------------------------------------------
extern "C" void kernel_launch(void* const* d_in, const int* in_sizes, int n_in,
                              void* d_out, int out_size, void* d_ws, size_t ws_size,
                              hipStream_t stream) {
  const float* hs    = (const float*)d_in[0];   // [B,S,H] f32
  const float* w_qkv = (const float*)d_in[1];   // [H, 6144] f32
  const float* w_o   = (const float*)d_in[2];   // [4096, H] f32
  const int*   pos   = (const int*)d_in[3];     // [B,S]
  float* out = (float*)d_out;                   // [B,S,H] f32 (reference output dtype)

  char* ws = (char*)d_ws;
  // workspace layout (bytes); wT region reused (wqkvT then woT);
  // hsb aliases Q region (hsb dead after gemm1, Q written after); attnO aliases qkv
  constexpr size_t OFF_WT  = 0;                         // 48 MB max (6144*4096*2)
  constexpr size_t OFF_QKV = 50331648;                  // 48 MB
  constexpr size_t OFF_Q   = OFF_QKV + 50331648;        // 32 MB
  constexpr size_t OFF_K   = OFF_Q + 33554432;          // 8 MB
  constexpr size_t OFF_VT  = OFF_K + 8388608;           // 8 MB  (end ~144 MB)
  bf16_t* wT    = (bf16_t*)(ws + OFF_WT);
  bf16_t* qkv   = (bf16_t*)(ws + OFF_QKV);
  bf16_t* Qb    = (bf16_t*)(ws + OFF_Q);
  bf16_t* Kb    = (bf16_t*)(ws + OFF_K);
  bf16_t* Vtb   = (bf16_t*)(ws + OFF_VT);
  bf16_t* hsb   = Qb;    // alias: hsb consumed by gemm1 before Q is written
  bf16_t* attnO = qkv;   // alias: qkv dead after rope/v_transpose

  // 0) hsb = bf16(hs)
  convert_f32_bf16<<<dim3((B_ * S_ * H_ / 4) / 256), 256, 0, stream>>>(
      hs, hsb, B_ * S_ * H_ / 4);
  // 1) wT = bf16(w_qkv^T)  [6144][4096]
  transpose_f32_bf16<<<dim3(NQKV_ / 64, H_ / 64), 256, 0, stream>>>(
      w_qkv, wT, H_, NQKV_);
  // 2) qkv = hsb @ w_qkv   (M=4096, N=6144, K=4096)
  gemm_abt<bf16_t><<<dim3(NQKV_ / 128, (B_ * S_) / 128), 256, 0, stream>>>(
      hsb, wT, qkv, B_ * S_, NQKV_, H_);
  // 3) rope + q/k layout (overwrites hsb region with Q — hsb is dead now)
  rope_qk<<<dim3(B_ * S_), 256, 0, stream>>>(qkv, pos, Qb, Kb);
  // 4) v transpose
  v_transpose<<<dim3(S_ / 64, NKV_ * 2, B_), 256, 0, stream>>>(qkv, Vtb);
  // 5) wT = bf16(w_o^T)  [4096][4096] (reuses wT region, after gemm1 done)
  transpose_f32_bf16<<<dim3(H_ / 64, (NQ_ * D_) / 64), 256, 0, stream>>>(
      w_o, wT, NQ_ * D_, H_);
  // 6) attention -> attnO [B*S][4096]
  flash_attn<<<dim3(S_ / 64, NQ_, B_), 256, 0, stream>>>(Qb, Kb, Vtb, attnO);
  // 7) out = attnO @ w_o  (M=4096, N=4096, K=4096), f32 output
  gemm_abt<float><<<dim3(H_ / 128, (B_ * S_) / 128), 256, 0, stream>>>(
      attnO, wT, out, B_ * S_, H_, H_);

  (void)in_sizes; (void)n_in; (void)out_size; (void)ws_size;
}

// Round 4
// 1041.489 us; speedup vs baseline: 1.0743x; 1.0743x over previous
//
#include <hip/hip_runtime.h>
#include <hip/hip_bf16.h>
#include <stdint.h>

// Problem constants
#define B_  2
#define S_  2048
#define H_  4096
#define NQ_ 32
#define NKV_ 8
#define D_  128
#define NQKV_ 6144   // (NQ+2*NKV)*D

typedef __bf16 bf16_t;
typedef __bf16 bf16x4 __attribute__((ext_vector_type(4)));
typedef __bf16 bf16x8 __attribute__((ext_vector_type(8)));
typedef float  floatx4 __attribute__((ext_vector_type(4)));

#define GLOBAL_AS __attribute__((address_space(1)))
#define LDS_AS    __attribute__((address_space(3)))

// ---------------------------------------------------------------------------
// f32 -> bf16 elementwise convert (vectorized: 4 elems/thread)
// ---------------------------------------------------------------------------
__global__ __launch_bounds__(256) void convert_f32_bf16(
    const float* __restrict__ src, bf16_t* __restrict__ dst, int n4) {
  int i = blockIdx.x * 256 + threadIdx.x;
  if (i < n4) {
    float4 v = ((const float4*)src)[i];
    bf16_t o[4] = {(bf16_t)v.x, (bf16_t)v.y, (bf16_t)v.z, (bf16_t)v.w};
    ((uint64_t*)dst)[i] = *(const uint64_t*)o;
  }
}

// ---------------------------------------------------------------------------
// Transpose + convert: src f32 [R][C] -> dst bf16 [C][R], 64x64 LDS tiles
// ---------------------------------------------------------------------------
__global__ __launch_bounds__(256) void transpose_f32_bf16(
    const float* __restrict__ src, bf16_t* __restrict__ dst, int R, int C) {
  __shared__ bf16_t tile[64][65];
  const int ct = blockIdx.x * 64, rt = blockIdx.y * 64;
  const int t = threadIdx.x;
  const int cl = t & 63;
  for (int i = 0; i < 16; ++i) {
    int rl = i * 4 + (t >> 6);
    tile[rl][cl] = (bf16_t)src[(size_t)(rt + rl) * C + ct + cl];
  }
  __syncthreads();
  const int rl2 = t & 63;
  for (int i = 0; i < 16; ++i) {
    int cl2 = i * 4 + (t >> 6);
    dst[(size_t)(ct + cl2) * R + rt + rl2] = tile[rl2][cl2];
  }
}

// ---------------------------------------------------------------------------
// GEMM: C[M,N] = A[M,K] * Bt[N,K]^T   (bf16 in, OutT out, fp32 accum)
// m97 structure: 128x128 tile, BK=32, 4 waves each 64x64 (4x4 of 16x16),
// global_load_lds width 16 staging.
// ---------------------------------------------------------------------------
template <typename OutT>
__global__ __launch_bounds__(256) void gemm_abt(
    const bf16_t* __restrict__ A, const bf16_t* __restrict__ Bt,
    OutT* __restrict__ C, int M, int N, int K) {
  __shared__ __align__(16) bf16_t lA[128 * 32];
  __shared__ __align__(16) bf16_t lB[128 * 32];
  const int tid = threadIdx.x;
  const int wave = tid >> 6, lane = tid & 63;
  const int lrow = lane & 15, quad = lane >> 4;
  const int row0 = blockIdx.y * 128, col0 = blockIdx.x * 128;
  const int wm = (wave >> 1) * 64, wn = (wave & 1) * 64;
  const int rA = lane >> 2;        // row-in-chunk = lane/4
  const int kA = (lane & 3) * 8;   // k offset = (lane%4)*8

  floatx4 acc[4][4] = {};

  for (int kt = 0; kt < K; kt += 32) {
    __syncthreads();
    for (int j = 0; j < 2; ++j) {
      const int c = wave * 2 + j;  // chunk 0..7, wave-uniform
      const bf16_t* ga = A  + (size_t)(row0 + c * 16 + rA) * K + kt + kA;
      const bf16_t* gb = Bt + (size_t)(col0 + c * 16 + rA) * K + kt + kA;
      __builtin_amdgcn_global_load_lds((GLOBAL_AS void*)ga,
                                       (LDS_AS void*)(lA + c * 512), 16, 0, 0);
      __builtin_amdgcn_global_load_lds((GLOBAL_AS void*)gb,
                                       (LDS_AS void*)(lB + c * 512), 16, 0, 0);
    }
    __syncthreads();
    bf16x8 af[4], bfr[4];
    for (int i = 0; i < 4; ++i)
      af[i] = *(const bf16x8*)(lA + (wm + i * 16 + lrow) * 32 + quad * 8);
    for (int j = 0; j < 4; ++j)
      bfr[j] = *(const bf16x8*)(lB + (wn + j * 16 + lrow) * 32 + quad * 8);
    for (int i = 0; i < 4; ++i)
      for (int j = 0; j < 4; ++j)
        acc[i][j] = __builtin_amdgcn_mfma_f32_16x16x32_bf16(af[i], bfr[j],
                                                            acc[i][j], 0, 0, 0);
  }

  // epilogue: C/D layout col=lane&15, row=quad*4+reg
  for (int i = 0; i < 4; ++i)
    for (int j = 0; j < 4; ++j)
      for (int r = 0; r < 4; ++r) {
        int row = row0 + wm + i * 16 + quad * 4 + r;
        int col = col0 + wn + j * 16 + lrow;
        C[(size_t)row * N + col] = (OutT)acc[i][j][r];
      }
}

// ---------------------------------------------------------------------------
// RoPE (GPT-J interleaved) on q,k + layout transform
// qkv[B*S][6144] -> Q[B][NQ][S][D], K[B][NKV][S][D]
// ---------------------------------------------------------------------------
__global__ __launch_bounds__(256) void rope_qk(
    const bf16_t* __restrict__ qkv, const int* __restrict__ positions,
    bf16_t* __restrict__ Q, bf16_t* __restrict__ K) {
  const int row = blockIdx.x;                 // b*S + s
  const int b = row >> 11, s = row & (S_ - 1);
  const float pos = (float)positions[row];
  const bf16_t* src = qkv + (size_t)row * NQKV_;
  for (int p = threadIdx.x; p < (NQ_ + NKV_) * 64; p += 256) {
    const int head = p >> 6, i = p & 63;
    const float inv = __powf(10000.0f, -(float)i * (1.0f / 64.0f));
    const float f = pos * inv;
    const float cs = __cosf(f), sn = __sinf(f);
    const float x1 = (float)src[head * 128 + 2 * i];
    const float x2 = (float)src[head * 128 + 2 * i + 1];
    const float o1 = x1 * cs - x2 * sn;
    const float o2 = x2 * cs + x1 * sn;
    bf16_t* dst;
    if (head < NQ_)
      dst = Q + ((size_t)(b * NQ_ + head) * S_ + s) * D_ + 2 * i;
    else
      dst = K + ((size_t)(b * NKV_ + (head - NQ_)) * S_ + s) * D_ + 2 * i;
    dst[0] = (bf16_t)o1;
    dst[1] = (bf16_t)o2;
  }
}

// ---------------------------------------------------------------------------
// Extract V from qkv and transpose: qkv cols [5120,6144) -> Vt[B][NKV][D][S]
// ---------------------------------------------------------------------------
__global__ __launch_bounds__(256) void v_transpose(
    const bf16_t* __restrict__ qkv, bf16_t* __restrict__ Vt) {
  __shared__ bf16_t tile[64][65];
  const int b = blockIdx.z;
  const int kh = blockIdx.y >> 1;
  const int dt = (blockIdx.y & 1) * 64;
  const int st = blockIdx.x * 64;
  const int t = threadIdx.x;
  const int colbase = (NQ_ + NKV_) * D_ + kh * D_ + dt;  // 5120 + ...
  for (int i = 0; i < 16; ++i) {
    int sl = i * 4 + (t >> 6);
    int dl = t & 63;
    tile[sl][dl] = qkv[(size_t)(b * S_ + st + sl) * NQKV_ + colbase + dl];
  }
  __syncthreads();
  for (int i = 0; i < 16; ++i) {
    int dl = i * 4 + (t >> 6);
    int sl = t & 63;
    Vt[((size_t)(b * NKV_ + kh) * D_ + dt + dl) * S_ + st + sl] = tile[sl][dl];
  }
}

// ---------------------------------------------------------------------------
// Flash attention (S^T formulation): causal, GQA (kh = h/4), online softmax.
// Computes S^T = K Q^T per wave (16 q-rows, q = lane&15), so row reductions
// are 2 shuffle rounds instead of 8, and P^T stores/reads are vectorized.
// O^T = V^T P^T accumulated in C-layout (m=d, n=q).
// Q[B][NQ][S][D], K[B][NKV][S][D], Vt[B][NKV][D][S] -> O[B][S][NQ*D]
// ---------------------------------------------------------------------------
__global__ __launch_bounds__(256) void flash_attn(
    const bf16_t* __restrict__ Q, const bf16_t* __restrict__ K,
    const bf16_t* __restrict__ Vt, bf16_t* __restrict__ O) {
  const int qt = blockIdx.x;   // q tile 0..31
  const int h  = blockIdx.y;   // 0..31
  const int b  = blockIdx.z;   // 0..1
  const int kh = h >> 2;
  const int tid = threadIdx.x, wave = tid >> 6, lane = tid & 63;
  const int lrow = lane & 15, quad = lane >> 4;
  const int q0 = qt * 64;

  __shared__ __align__(16) bf16_t lK[64][136];    // [s][d] padded
  __shared__ __align__(16) bf16_t lV[128][72];    // [d][s] padded
  __shared__ __align__(16) bf16_t lPt[64][136];   // [q_local][s_local] padded

  const bf16_t* Qbase = Q  + ((size_t)(b * NQ_ + h) * S_) * D_;
  const bf16_t* Kbase = K  + ((size_t)(b * NKV_ + kh) * S_) * D_;
  const bf16_t* Vbase = Vt + ((size_t)(b * NKV_ + kh) * D_) * S_;

  // Q fragment (B-operand): lane holds Q[q=qrow][d=ks*32+quad*8+j]
  const int qrow = q0 + wave * 16 + lrow;
  bf16x8 qf[4];
  {
    const bf16_t* qp = Qbase + (size_t)qrow * D_ + quad * 8;
    for (int ks = 0; ks < 4; ++ks) qf[ks] = *(const bf16x8*)(qp + ks * 32);
  }

  floatx4 acc[8] = {};   // O^T[d = dt*16 + quad*4 + r][q = lrow]
  float mrun = -3.0e38f, lrun = 0.0f;
  const float scale = 0.08838834764831845f;  // 1/sqrt(128)

  const int nkt = qt + 1;
  for (int kt = 0; kt < nkt; ++kt) {
    const int k0 = kt * 64;
    __syncthreads();
    // stage K tile 64x128
    for (int it = 0; it < 4; ++it) {
      int idx = tid + it * 256;
      int r = idx >> 4;
      int d = (idx & 15) * 8;
      *(bf16x8*)&lK[r][d] = *(const bf16x8*)(Kbase + (size_t)(k0 + r) * D_ + d);
    }
    // stage V^T tile 128x64
    for (int it = 0; it < 4; ++it) {
      int idx = tid + it * 256;
      int d = idx >> 3;
      int s = (idx & 7) * 8;
      *(bf16x8*)&lV[d][s] = *(const bf16x8*)(Vbase + (size_t)d * S_ + k0 + s);
    }
    __syncthreads();

    // S^T = K Q^T : A = K m-tiles (k-pos), B = Q. Lane holds
    // S^T[k = k0 + t*16 + quad*4 + r][q = qrow].
    floatx4 sacc[4];
    for (int t = 0; t < 4; ++t) {
      floatx4 a = {0.f, 0.f, 0.f, 0.f};
      for (int ks = 0; ks < 4; ++ks) {
        bf16x8 kf = *(const bf16x8*)&lK[t * 16 + lrow][ks * 32 + quad * 8];
        a = __builtin_amdgcn_mfma_f32_16x16x32_bf16(kf, qf[ks], a, 0, 0, 0);
      }
      sacc[t] = a;
    }

    // scale + causal mask + in-lane max over 16 values
    float mx = -3.0e38f;
    for (int t = 0; t < 4; ++t)
      for (int r = 0; r < 4; ++r) {
        float v = sacc[t][r] * scale;
        const int kpos = k0 + t * 16 + quad * 4 + r;
        v = (kpos > qrow) ? -1.0e30f : v;
        sacc[t][r] = v;
        mx = fmaxf(mx, v);
      }
    // cross-lane over quads only (same lrow): 2 rounds
    mx = fmaxf(mx, __shfl_xor(mx, 16));
    mx = fmaxf(mx, __shfl_xor(mx, 32));
    const float mnew = fmaxf(mrun, mx);
    const float alpha = __expf(mrun - mnew);
    float rs = 0.0f;
    for (int t = 0; t < 4; ++t) {
      bf16x4 pk;
      for (int r = 0; r < 4; ++r) {
        float p = __expf(sacc[t][r] - mnew);
        rs += p;
        pk[r] = (bf16_t)p;
      }
      // P^T row-major per q-row: 4 consecutive k at col t*16+quad*4
      *(bf16x4*)&lPt[wave * 16 + lrow][t * 16 + quad * 4] = pk;
    }
    rs += __shfl_xor(rs, 16);
    rs += __shfl_xor(rs, 32);
    lrun = lrun * alpha + rs;
    mrun = mnew;
    for (int dt = 0; dt < 8; ++dt) acc[dt] *= alpha;

    // O^T += V^T P^T (A = V^T, B = P^T). Wave-synchronous lPt use (own rows).
    bf16x8 pf0 = *(const bf16x8*)&lPt[wave * 16 + lrow][quad * 8];
    bf16x8 pf1 = *(const bf16x8*)&lPt[wave * 16 + lrow][32 + quad * 8];
    for (int dt = 0; dt < 8; ++dt) {
      bf16x8 v0 = *(const bf16x8*)&lV[dt * 16 + lrow][quad * 8];
      bf16x8 v1 = *(const bf16x8*)&lV[dt * 16 + lrow][32 + quad * 8];
      floatx4 a = acc[dt];
      a = __builtin_amdgcn_mfma_f32_16x16x32_bf16(v0, pf0, a, 0, 0, 0);
      a = __builtin_amdgcn_mfma_f32_16x16x32_bf16(v1, pf1, a, 0, 0, 0);
      acc[dt] = a;
    }
  }

  // epilogue: O[b][qrow][h*128 + d], d = dt*16 + quad*4 + r, /= lrun
  const float inv_l = 1.0f / lrun;
  bf16_t* Obase = O + ((size_t)(b * S_) + qrow) * (NQ_ * D_) + h * D_;
  for (int dt = 0; dt < 8; ++dt) {
    bf16x4 ov;
    for (int r = 0; r < 4; ++r) ov[r] = (bf16_t)(acc[dt][r] * inv_l);
    *(bf16x4*)(Obase + dt * 16 + quad * 4) = ov;
  }
}

// ---------------------------------------------------------------------------
// Launch
// ---------------------------------------------------------------------------
extern "C" void kernel_launch(void* const* d_in, const int* in_sizes, int n_in,
                              void* d_out, int out_size, void* d_ws, size_t ws_size,
                              hipStream_t stream) {
  const float* hs    = (const float*)d_in[0];   // [B,S,H] f32
  const float* w_qkv = (const float*)d_in[1];   // [H, 6144] f32
  const float* w_o   = (const float*)d_in[2];   // [4096, H] f32
  const int*   pos   = (const int*)d_in[3];     // [B,S]
  float* out = (float*)d_out;                   // [B,S,H] f32

  char* ws = (char*)d_ws;
  constexpr size_t OFF_WT  = 0;                         // 48 MB max
  constexpr size_t OFF_QKV = 50331648;                  // 48 MB
  constexpr size_t OFF_Q   = OFF_QKV + 50331648;        // 32 MB
  constexpr size_t OFF_K   = OFF_Q + 33554432;          // 8 MB
  constexpr size_t OFF_VT  = OFF_K + 8388608;           // 8 MB (end ~144 MB)
  bf16_t* wT    = (bf16_t*)(ws + OFF_WT);
  bf16_t* qkv   = (bf16_t*)(ws + OFF_QKV);
  bf16_t* Qb    = (bf16_t*)(ws + OFF_Q);
  bf16_t* Kb    = (bf16_t*)(ws + OFF_K);
  bf16_t* Vtb   = (bf16_t*)(ws + OFF_VT);
  bf16_t* hsb   = Qb;    // alias: hsb consumed by gemm1 before Q is written
  bf16_t* attnO = qkv;   // alias: qkv dead after rope/v_transpose

  // 0) hsb = bf16(hs)
  convert_f32_bf16<<<dim3((B_ * S_ * H_ / 4) / 256), 256, 0, stream>>>(
      hs, hsb, B_ * S_ * H_ / 4);
  // 1) wT = bf16(w_qkv^T)  [6144][4096]
  transpose_f32_bf16<<<dim3(NQKV_ / 64, H_ / 64), 256, 0, stream>>>(
      w_qkv, wT, H_, NQKV_);
  // 2) qkv = hsb @ w_qkv   (M=4096, N=6144, K=4096)
  gemm_abt<bf16_t><<<dim3(NQKV_ / 128, (B_ * S_) / 128), 256, 0, stream>>>(
      hsb, wT, qkv, B_ * S_, NQKV_, H_);
  // 3) rope + q/k layout (overwrites hsb region with Q — hsb is dead now)
  rope_qk<<<dim3(B_ * S_), 256, 0, stream>>>(qkv, pos, Qb, Kb);
  // 4) v transpose
  v_transpose<<<dim3(S_ / 64, NKV_ * 2, B_), 256, 0, stream>>>(qkv, Vtb);
  // 5) wT = bf16(w_o^T)  [4096][4096]
  transpose_f32_bf16<<<dim3(H_ / 64, (NQ_ * D_) / 64), 256, 0, stream>>>(
      w_o, wT, NQ_ * D_, H_);
  // 6) attention -> attnO [B*S][4096]
  flash_attn<<<dim3(S_ / 64, NQ_, B_), 256, 0, stream>>>(Qb, Kb, Vtb, attnO);
  // 7) out = attnO @ w_o  (M=4096, N=4096, K=4096), f32 output
  gemm_abt<float><<<dim3(H_ / 128, (B_ * S_) / 128), 256, 0, stream>>>(
      attnO, wT, out, B_ * S_, H_, H_);

  (void)in_sizes; (void)n_in; (void)out_size; (void)ws_size;
}